// Round 4
// baseline (208.153 us; speedup 1.0000x reference)
//
#include <hip/hip_runtime.h>
#include <math.h>

#define B_SZ 4096
#define N_SZ 200
#define K_SZ 64
#define H1 80
#define H2 40
#define NEG_V (-4294967295.0f)

#define ROWS 256   // rows per block; 4 waves x 4 m-tiles
#define A2S 104    // A2 row stride in halves: 208B = 13*16 (aligned)

typedef _Float16 f16x8 __attribute__((ext_vector_type(8)));
typedef _Float16 f16x4 __attribute__((ext_vector_type(4)));
typedef float f32x4 __attribute__((ext_vector_type(4)));

// ---------------- qW[b][h] = b1[h] + sum_i q[b][i]*(W1[i][h]+W1[128+i][h])  (exact fp32)
__global__ __launch_bounds__(128) void qw_kernel(const float* __restrict__ query,
                                                 const float* __restrict__ W1,
                                                 const float* __restrict__ b1,
                                                 float* __restrict__ qW) {
    int b = blockIdx.x;
    int tid = threadIdx.x;
    __shared__ float sq[K_SZ];
    if (tid < K_SZ) sq[tid] = query[b * K_SZ + tid];
    __syncthreads();
    if (tid < H1) {
        float acc = b1[tid];
#pragma unroll 8
        for (int i = 0; i < K_SZ; ++i)
            acc += sq[i] * (W1[i * H1 + tid] + W1[(128 + i) * H1 + tid]);
        qW[b * H1 + tid] = acc;
    }
}

// ---------------- pack layer-1/2 weights, MFMA B-fragment order, hi|lo interleaved
// frag granularity: (f*64+l)*16 + j (hi) / +8+j (lo)
__global__ __launch_bounds__(256) void prep_bp(const float* __restrict__ W1,
                                               const float* __restrict__ W2,
                                               _Float16* __restrict__ Bp1,
                                               _Float16* __restrict__ Bp2) {
    int idx = blockIdx.x * 256 + threadIdx.x;
    if (idx < 5 * 4 * 64 * 8) {                 // layer1: f = ht*4+ks, 20 frags
        int j = idx & 7, lane = (idx >> 3) & 63, f = idx >> 9;
        int ks = f & 3, ht = f >> 2;
        int k = ks * 32 + (lane >> 4) * 8 + j;  // 0..127: 0-63 k-coef, 64-127 q*k-coef
        int h = ht * 16 + (lane & 15);
        float w = (k < 64) ? (W1[(64 + k) * H1 + h] - W1[(128 + k) * H1 + h])
                           : W1[(192 + (k - 64)) * H1 + h];
        _Float16 hi = (_Float16)w;
        Bp1[(f * 64 + lane) * 16 + j] = hi;
        Bp1[(f * 64 + lane) * 16 + 8 + j] = (_Float16)(w - (float)hi);
    } else {
        int idx2 = idx - 5 * 4 * 64 * 8;
        if (idx2 < 9 * 64 * 8) {                // layer2: f2 = ht2*3+ks2, 9 frags
            int j = idx2 & 7, lane = (idx2 >> 3) & 63, f2 = idx2 >> 9;
            int ks2 = f2 % 3, ht2 = f2 / 3;
            int k2 = ks2 * 32 + (lane >> 4) * 8 + j;
            int m = ht2 * 16 + (lane & 15);
            float w = (k2 < H1 && m < H2) ? W2[k2 * H2 + m] : 0.0f;
            _Float16 hi = (_Float16)w;
            Bp2[(f2 * 64 + lane) * 16 + j] = hi;
            Bp2[(f2 * 64 + lane) * 16 + 8 + j] = (_Float16)(w - (float)hi);
        }
    }
}

// ---------------- fused MFMA score kernel: 256 rows/block, 4 waves x 4 m-tiles
__global__ __launch_bounds__(256, 2) void score_mfma(
    const float* __restrict__ query, const float* __restrict__ key,
    const int* __restrict__ mask,
    const _Float16* __restrict__ Bp1, const _Float16* __restrict__ Bp2,
    const float* __restrict__ a1, const float* __restrict__ b2,
    const float* __restrict__ a2, const float* __restrict__ Wo,
    const float* __restrict__ bo,
    const float* __restrict__ qW, float* __restrict__ scores) {
    __shared__ _Float16 smemA[ROWS * 128];   // 64 KB A1 (swizzled) -> reused as A2 [256][A2S]
    __shared__ float sq[3 * K_SZ];
    __shared__ float sqW[3 * H1];
    __shared__ float sa1[H1];
    __shared__ float sb2[48], sa2[48], sWo[48];
    __shared__ float ssc[ROWS];

    const int tid = threadIdx.x;
    const int wv = tid >> 6;
    const int l = tid & 63;
    const int l15 = l & 15;
    const int lg = l >> 4;
    const int p0 = blockIdx.x * ROWS;
    const int bfirst = p0 / N_SZ;
    const int bs1 = (bfirst + 1) * N_SZ - p0;   // local row where b increments
    const int bs2 = bs1 + N_SZ;

    // ---- stage params
    for (int i = tid; i < 3 * K_SZ; i += 256) {
        int bb = bfirst + i / K_SZ;
        sq[i] = (bb < B_SZ) ? query[bb * K_SZ + (i & 63)] : 0.0f;
    }
    for (int i = tid; i < 3 * H1; i += 256) {
        int bb = bfirst + i / H1;
        sqW[i] = (bb < B_SZ) ? qW[bb * H1 + i % H1] : 0.0f;
    }
    for (int i = tid; i < H1; i += 256) sa1[i] = a1[i];
    for (int i = tid; i < 48; i += 256) {
        sb2[i] = (i < H2) ? b2[i] : 0.0f;
        sa2[i] = (i < H2) ? a2[i] : 0.0f;
        sWo[i] = (i < H2) ? Wo[i] : 0.0f;
    }
    __syncthreads();

    // ---- stage A1: [row][i] fp16, i<64 = k, i>=64 = q*k; 16B XOR-swizzled
#pragma unroll 4
    for (int r = 0; r < 16; ++r) {
        int idx = r * 256 + tid;          // 0..4095
        int trow = idx >> 4;
        int c4 = idx & 15;
        float4 kv = *reinterpret_cast<const float4*>(&key[((size_t)(p0 + trow)) * K_SZ + c4 * 4]);
        int lb = (trow >= bs1) + (trow >= bs2);
        float4 qv = *reinterpret_cast<const float4*>(&sq[lb * K_SZ + c4 * 4]);
        int base = trow * 128 + c4 * 4;
        int sw = (trow & 7) << 3;         // XOR in 8-half (16B) units
        f16x4 kk, qk;
        kk[0] = (_Float16)kv.x; kk[1] = (_Float16)kv.y; kk[2] = (_Float16)kv.z; kk[3] = (_Float16)kv.w;
        qk[0] = (_Float16)(qv.x * kv.x); qk[1] = (_Float16)(qv.y * kv.y);
        qk[2] = (_Float16)(qv.z * kv.z); qk[3] = (_Float16)(qv.w * kv.w);
        *reinterpret_cast<f16x4*>(&smemA[base ^ sw]) = kk;
        *reinterpret_cast<f16x4*>(&smemA[(base + 64) ^ sw]) = qk;
    }
    __syncthreads();

    // ---- layer 1: C1[256 x 80] = A1[256 x 128] @ B1[128 x 80], B hi/lo split
    f32x4 acc[4][5];
#pragma unroll
    for (int mt = 0; mt < 4; ++mt)
#pragma unroll
        for (int ht = 0; ht < 5; ++ht) acc[mt][ht] = (f32x4){0.f, 0.f, 0.f, 0.f};

#pragma unroll
    for (int ks = 0; ks < 4; ++ks) {
        f16x8 af[4];
#pragma unroll
        for (int mt = 0; mt < 4; ++mt) {
            int row = wv * 64 + mt * 16 + l15;
            int hidx = (row * 128 + ks * 32 + lg * 8) ^ ((row & 7) << 3);
            af[mt] = *reinterpret_cast<const f16x8*>(&smemA[hidx]);
        }
#pragma unroll
        for (int ht = 0; ht < 5; ++ht) {
            int bidx = ((ht * 4 + ks) * 64 + l) * 16;
            f16x8 bh = *reinterpret_cast<const f16x8*>(&Bp1[bidx]);
            f16x8 bl = *reinterpret_cast<const f16x8*>(&Bp1[bidx + 8]);
#pragma unroll
            for (int mt = 0; mt < 4; ++mt) {
                acc[mt][ht] = __builtin_amdgcn_mfma_f32_16x16x32_f16(af[mt], bh, acc[mt][ht], 0, 0, 0);
                acc[mt][ht] = __builtin_amdgcn_mfma_f32_16x16x32_f16(af[mt], bl, acc[mt][ht], 0, 0, 0);
            }
        }
    }
    __syncthreads();   // all A1 reads complete before overwriting as A2

    // ---- epilogue 1: h1 = prelu(C1 + qW) -> A2 [row][h] fp16, stride A2S
    _Float16* A2 = smemA;
#pragma unroll
    for (int mt = 0; mt < 4; ++mt) {
#pragma unroll
        for (int ht = 0; ht < 5; ++ht) {
            int h = ht * 16 + l15;
            float aa = sa1[h];
#pragma unroll
            for (int j = 0; j < 4; ++j) {
                int n = wv * 64 + mt * 16 + lg * 4 + j;
                int lb = (n >= bs1) + (n >= bs2);
                float v = acc[mt][ht][j] + sqW[lb * H1 + h];
                float pre = (v > 0.0f) ? v : v * aa;
                A2[n * A2S + h] = (_Float16)pre;
            }
        }
    }
    // zero-pad A2 cols 80..95 (read by ks2=2): 256 rows x 16 halves
    {
        f16x8 zz = {};
#pragma unroll
        for (int z = 0; z < 2; ++z) {
            int idx = z * 256 + tid;      // 0..511
            int row = idx >> 1, half8 = idx & 1;
            *reinterpret_cast<f16x8*>(&A2[row * A2S + 80 + half8 * 8]) = zz;
        }
    }
    __syncthreads();

    // ---- layer 2: C2[256 x 48] = A2[256 x 96] @ B2[96 x 48], B hi/lo split
    f32x4 acc2[4][3];
#pragma unroll
    for (int mt = 0; mt < 4; ++mt)
#pragma unroll
        for (int ht = 0; ht < 3; ++ht) acc2[mt][ht] = (f32x4){0.f, 0.f, 0.f, 0.f};

#pragma unroll
    for (int ks = 0; ks < 3; ++ks) {
        f16x8 a2f[4];
#pragma unroll
        for (int mt = 0; mt < 4; ++mt) {
            int row = wv * 64 + mt * 16 + l15;
            a2f[mt] = *reinterpret_cast<const f16x8*>(&A2[row * A2S + ks * 32 + lg * 8]);
        }
#pragma unroll
        for (int ht = 0; ht < 3; ++ht) {
            int bidx = ((ht * 3 + ks) * 64 + l) * 16;
            f16x8 bh = *reinterpret_cast<const f16x8*>(&Bp2[bidx]);
            f16x8 bl = *reinterpret_cast<const f16x8*>(&Bp2[bidx + 8]);
#pragma unroll
            for (int mt = 0; mt < 4; ++mt) {
                acc2[mt][ht] = __builtin_amdgcn_mfma_f32_16x16x32_f16(a2f[mt], bh, acc2[mt][ht], 0, 0, 0);
                acc2[mt][ht] = __builtin_amdgcn_mfma_f32_16x16x32_f16(a2f[mt], bl, acc2[mt][ht], 0, 0, 0);
            }
        }
    }

    // ---- epilogue 2 + layer 3: score = Wo . prelu(C2 + b2), 16-lane shfl reduce
    float bov = bo[0];
#pragma unroll
    for (int mt = 0; mt < 4; ++mt) {
#pragma unroll
        for (int j = 0; j < 4; ++j) {
            float psum = 0.0f;
#pragma unroll
            for (int ht = 0; ht < 3; ++ht) {
                int m = ht * 16 + l15;
                float v = acc2[mt][ht][j] + sb2[m];
                float pre = (v > 0.0f) ? v : v * sa2[m];
                psum += pre * sWo[m];   // sWo[m>=40] = 0
            }
            psum += __shfl_xor(psum, 1);
            psum += __shfl_xor(psum, 2);
            psum += __shfl_xor(psum, 4);
            psum += __shfl_xor(psum, 8);
            if (l15 == 0) ssc[wv * 64 + mt * 16 + lg * 4 + j] = psum;
        }
    }
    __syncthreads();
    {
        int p = p0 + tid;
        float sc = ssc[tid] + bov;
        scores[p] = (mask[p] == 0) ? NEG_V : sc;
    }
}

// ---------------- softmax over N + weighted value sum
__global__ __launch_bounds__(256) void softmax_out_kernel(
    const float* __restrict__ scores, const float* __restrict__ value,
    float* __restrict__ out) {
    int b = blockIdx.x;
    int tid = threadIdx.x;
    __shared__ float sprob[256];
    __shared__ float sred[8];
    __shared__ float spart[4 * K_SZ];

    float s = (tid < N_SZ) ? scores[b * N_SZ + tid] : -INFINITY;
    float m = s;
#pragma unroll
    for (int off = 32; off >= 1; off >>= 1) m = fmaxf(m, __shfl_xor(m, off));
    if ((tid & 63) == 0) sred[tid >> 6] = m;
    __syncthreads();
    m = fmaxf(fmaxf(sred[0], sred[1]), fmaxf(sred[2], sred[3]));

    float e = (tid < N_SZ) ? expf(s - m) : 0.0f;
    sprob[tid] = e;
    float t = e;
#pragma unroll
    for (int off = 32; off >= 1; off >>= 1) t += __shfl_xor(t, off);
    if ((tid & 63) == 0) sred[4 + (tid >> 6)] = t;
    __syncthreads();
    float inv = 1.0f / (sred[4] + sred[5] + sred[6] + sred[7]);

    int w = tid >> 6;
    int l = tid & 63;
    float acc0 = 0.0f, acc1v = 0.0f;
#pragma unroll 5
    for (int jj = 0; jj < 50; jj += 2) {
        int n = w * 50 + jj;
        acc0  += sprob[n]     * value[((size_t)b * N_SZ + n)     * K_SZ + l];
        acc1v += sprob[n + 1] * value[((size_t)b * N_SZ + n + 1) * K_SZ + l];
    }
    spart[w * K_SZ + l] = acc0 + acc1v;
    __syncthreads();
    if (tid < K_SZ) {
        out[b * K_SZ + tid] =
            (spart[tid] + spart[64 + tid] + spart[128 + tid] + spart[192 + tid]) * inv;
    }
}

extern "C" void kernel_launch(void* const* d_in, const int* in_sizes, int n_in,
                              void* d_out, int out_size, void* d_ws, size_t ws_size,
                              hipStream_t stream) {
    const float* query = (const float*)d_in[0];
    const float* key   = (const float*)d_in[1];
    const float* value = (const float*)d_in[2];
    const int*   mask  = (const int*)d_in[3];
    const float* W1    = (const float*)d_in[4];
    const float* b1    = (const float*)d_in[5];
    const float* a1    = (const float*)d_in[6];
    const float* W2    = (const float*)d_in[7];
    const float* b2    = (const float*)d_in[8];
    const float* a2    = (const float*)d_in[9];
    const float* Wo    = (const float*)d_in[10];
    const float* bo    = (const float*)d_in[11];
    float* out = (float*)d_out;

    float* qW     = (float*)d_ws;                        // B*H1 floats
    float* scores = qW + (size_t)B_SZ * H1;              // B*N floats
    _Float16* Bp1 = (_Float16*)(scores + (size_t)B_SZ * N_SZ);  // 20*64*16 halves
    _Float16* Bp2 = Bp1 + 20 * 64 * 16;                  // 9*64*16 halves

    qw_kernel<<<B_SZ, 128, 0, stream>>>(query, W1, b1, qW);
    prep_bp<<<58, 256, 0, stream>>>(W1, W2, Bp1, Bp2);
    score_mfma<<<(B_SZ * N_SZ) / ROWS, 256, 0, stream>>>(
        query, key, mask, Bp1, Bp2, a1, b2, a2, Wo, bo, qW, scores);
    softmax_out_kernel<<<B_SZ, 256, 0, stream>>>(scores, value, out);
}

// Round 5
// 164.293 us; speedup vs baseline: 1.2670x; 1.2670x over previous
//
#include <hip/hip_runtime.h>
#include <math.h>

#define B_SZ 4096
#define N_SZ 200
#define K_SZ 64
#define H1 80
#define H2 40
#define NEG_V (-4294967295.0f)

#define ROWS 128   // rows per block: 4 waves x 2 n-tiles x 16

typedef _Float16 f16x8 __attribute__((ext_vector_type(8)));
typedef float f32x4 __attribute__((ext_vector_type(4)));
typedef unsigned int u32;

union H2U { _Float16 h[2]; u32 u; };
union U4F { u32 u[4]; f16x8 v; };

// ---------------- qW[b][h] = b1[h] + sum_i q[b][i]*(W1[i][h]+W1[128+i][h])  (exact fp32)
__global__ __launch_bounds__(128) void qw_kernel(const float* __restrict__ query,
                                                 const float* __restrict__ W1,
                                                 const float* __restrict__ b1,
                                                 float* __restrict__ qW) {
    int b = blockIdx.x;
    int tid = threadIdx.x;
    __shared__ float sq[K_SZ];
    if (tid < K_SZ) sq[tid] = query[b * K_SZ + tid];
    __syncthreads();
    if (tid < H1) {
        float acc = b1[tid];
#pragma unroll 8
        for (int i = 0; i < K_SZ; ++i)
            acc += sq[i] * (W1[i * H1 + tid] + W1[(128 + i) * H1 + tid]);
        qW[b * H1 + tid] = acc;
    }
}

// ---------------- pack layer-1/2 weights (A-operand of swapped MFMA), hi|lo interleaved
// frag: lane l, elem j holds W[k = ks*32 + (l>>4)*8 + j][feat = ht*16 + (l&15)]
__global__ __launch_bounds__(256) void prep_bp(const float* __restrict__ W1,
                                               const float* __restrict__ W2,
                                               _Float16* __restrict__ Bp1,
                                               _Float16* __restrict__ Bp2) {
    int idx = blockIdx.x * 256 + threadIdx.x;
    if (idx < 5 * 4 * 64 * 8) {                 // layer1: f = ht*4+ks, 20 frags
        int j = idx & 7, lane = (idx >> 3) & 63, f = idx >> 9;
        int ks = f & 3, ht = f >> 2;
        int k = ks * 32 + (lane >> 4) * 8 + j;  // 0..127: 0-63 k-coef, 64-127 q*k-coef
        int h = ht * 16 + (lane & 15);
        float w = (k < 64) ? (W1[(64 + k) * H1 + h] - W1[(128 + k) * H1 + h])
                           : W1[(192 + (k - 64)) * H1 + h];
        _Float16 hi = (_Float16)w;
        Bp1[(f * 64 + lane) * 16 + j] = hi;
        Bp1[(f * 64 + lane) * 16 + 8 + j] = (_Float16)(w - (float)hi);
    } else {
        int idx2 = idx - 5 * 4 * 64 * 8;
        if (idx2 < 9 * 64 * 8) {                // layer2: f2 = ht2*3+ks2, 9 frags
            int j = idx2 & 7, lane = (idx2 >> 3) & 63, f2 = idx2 >> 9;
            int ks2 = f2 % 3, ht2 = f2 / 3;
            int k2 = ks2 * 32 + (lane >> 4) * 8 + j;
            int m = ht2 * 16 + (lane & 15);
            float w = (k2 < H1 && m < H2) ? W2[k2 * H2 + m] : 0.0f;
            _Float16 hi = (_Float16)w;
            Bp2[(f2 * 64 + lane) * 16 + j] = hi;
            Bp2[(f2 * 64 + lane) * 16 + 8 + j] = (_Float16)(w - (float)hi);
        }
    }
}

// ---------------- fused MFMA score kernel, operand-swapped: D = W^T-tiles @ feat-tiles
// 128 rows/block = 4 waves x 2 n-tiles; features loaded direct from global; no A-LDS.
__global__ __launch_bounds__(256, 4) void score_mfma(
    const float* __restrict__ query, const float* __restrict__ key,
    const int* __restrict__ mask,
    const _Float16* __restrict__ Bp1, const _Float16* __restrict__ Bp2,
    const float* __restrict__ a1, const float* __restrict__ b2,
    const float* __restrict__ a2, const float* __restrict__ Wo,
    const float* __restrict__ bo,
    const float* __restrict__ qW, float* __restrict__ scores) {
    __shared__ float sq[2 * K_SZ];     // 2 possible b rows per 128-row block
    __shared__ float sqW[2 * H1];
    __shared__ float sa1[H1];
    __shared__ float sb2[48], sa2[48], sWo[48];

    const int tid = threadIdx.x;
    const int wv = tid >> 6;
    const int l = tid & 63;
    const int l15 = l & 15;
    const int lg = l >> 4;
    const int p0 = blockIdx.x * ROWS;
    const int bfirst = p0 / N_SZ;
    const int bs1 = (bfirst + 1) * N_SZ - p0;   // local row where b increments (>72)

    // ---- stage params (tiny)
    for (int i = tid; i < 2 * K_SZ; i += 256) {
        int bb = bfirst + (i >> 6);
        sq[i] = (bb < B_SZ) ? query[bb * K_SZ + (i & 63)] : 0.0f;
    }
    for (int i = tid; i < 2 * H1; i += 256) {
        int bb = bfirst + i / H1;
        sqW[i] = (bb < B_SZ) ? qW[bb * H1 + i % H1] : 0.0f;
    }
    for (int i = tid; i < H1; i += 256) sa1[i] = a1[i];
    for (int i = tid; i < 48; i += 256) {
        sb2[i] = (i < H2) ? b2[i] : 0.0f;
        sa2[i] = (i < H2) ? a2[i] : 0.0f;
        sWo[i] = (i < H2) ? Wo[i] : 0.0f;
    }
    __syncthreads();

    // per-lane row handled (n = l15 within each n-tile)
    const int nl0 = wv * 32 + l15;        // nt=0 local row
    const int nl1 = nl0 + 16;             // nt=1 local row
    const int lb0 = (nl0 >= bs1) ? 1 : 0;
    const int lb1 = (nl1 >= bs1) ? 1 : 0;

    // ---- layer 1: D1[f][n] = sum_k W1c[k][f] * F[k][n]
    f32x4 D1[2][5];
#pragma unroll
    for (int nt = 0; nt < 2; ++nt)
#pragma unroll
        for (int ht = 0; ht < 5; ++ht) D1[nt][ht] = (f32x4){0.f, 0.f, 0.f, 0.f};

#pragma unroll
    for (int ksp = 0; ksp < 2; ++ksp) {
        // build B-frags for ks=ksp (k-part) and ks=ksp+2 (q*k-part), both n-tiles
        f16x8 Bk[2], Bqk[2];
#pragma unroll
        for (int nt = 0; nt < 2; ++nt) {
            int nloc = wv * 32 + nt * 16 + l15;
            int lb = (nloc >= bs1) ? 1 : 0;
            const float* kp = &key[(size_t)(p0 + nloc) * K_SZ + ksp * 32 + lg * 8];
            float4 k0 = *reinterpret_cast<const float4*>(kp);
            float4 k1 = *reinterpret_cast<const float4*>(kp + 4);
            const float* qp = &sq[lb * K_SZ + ksp * 32 + lg * 8];
            float4 q0 = *reinterpret_cast<const float4*>(qp);
            float4 q1 = *reinterpret_cast<const float4*>(qp + 4);
            f16x8 bk, bq;
            bk[0] = (_Float16)k0.x; bk[1] = (_Float16)k0.y; bk[2] = (_Float16)k0.z; bk[3] = (_Float16)k0.w;
            bk[4] = (_Float16)k1.x; bk[5] = (_Float16)k1.y; bk[6] = (_Float16)k1.z; bk[7] = (_Float16)k1.w;
            bq[0] = (_Float16)(q0.x * k0.x); bq[1] = (_Float16)(q0.y * k0.y);
            bq[2] = (_Float16)(q0.z * k0.z); bq[3] = (_Float16)(q0.w * k0.w);
            bq[4] = (_Float16)(q1.x * k1.x); bq[5] = (_Float16)(q1.y * k1.y);
            bq[6] = (_Float16)(q1.z * k1.z); bq[7] = (_Float16)(q1.w * k1.w);
            Bk[nt] = bk; Bqk[nt] = bq;
        }
#pragma unroll
        for (int ht = 0; ht < 5; ++ht) {
#pragma unroll
            for (int s = 0; s < 2; ++s) {
                int kk = ksp + s * 2;            // weight tile ks index
                int fidx = (ht * 4 + kk) * 64 + l;
                f16x8 wh = *reinterpret_cast<const f16x8*>(&Bp1[fidx * 16]);
                f16x8 wl = *reinterpret_cast<const f16x8*>(&Bp1[fidx * 16 + 8]);
#pragma unroll
                for (int nt = 0; nt < 2; ++nt) {
                    f16x8 bb = (s == 0) ? Bk[nt] : Bqk[nt];
                    D1[nt][ht] = __builtin_amdgcn_mfma_f32_16x16x32_f16(wh, bb, D1[nt][ht], 0, 0, 0);
                    D1[nt][ht] = __builtin_amdgcn_mfma_f32_16x16x32_f16(wl, bb, D1[nt][ht], 0, 0, 0);
                }
            }
        }
    }

    // ---- epilogue 1 (in-register): h1 = prelu(D1 + qW), pack to fp16 pairs
    // D1 lane layout: feat f = ht*16 + lg*4 + jj, n = ntbase + l15
    u32 pk[2][6][2];
#pragma unroll
    for (int nt = 0; nt < 2; ++nt) {
        int lb = nt ? lb1 : lb0;
#pragma unroll
        for (int ht = 0; ht < 5; ++ht) {
            float4 qw4 = *reinterpret_cast<const float4*>(&sqW[lb * H1 + ht * 16 + lg * 4]);
            float4 aa4 = *reinterpret_cast<const float4*>(&sa1[ht * 16 + lg * 4]);
            float h0 = D1[nt][ht][0] + qw4.x;
            float h1v = D1[nt][ht][1] + qw4.y;
            float h2 = D1[nt][ht][2] + qw4.z;
            float h3 = D1[nt][ht][3] + qw4.w;
            h0 = (h0 > 0.f) ? h0 : h0 * aa4.x;
            h1v = (h1v > 0.f) ? h1v : h1v * aa4.y;
            h2 = (h2 > 0.f) ? h2 : h2 * aa4.z;
            h3 = (h3 > 0.f) ? h3 : h3 * aa4.w;
            H2U u0, u1;
            u0.h[0] = (_Float16)h0; u0.h[1] = (_Float16)h1v;
            u1.h[0] = (_Float16)h2; u1.h[1] = (_Float16)h3;
            pk[nt][ht][0] = u0.u;
            pk[nt][ht][1] = u1.u;
        }
        pk[nt][5][0] = 0u; pk[nt][5][1] = 0u;   // zero-pad feats 80..95
    }

    // ---- layer 2: D2[m][n] = sum_k2 W2[k2][m] * h1[k2][n]
    f32x4 D2[2][3];
#pragma unroll
    for (int nt = 0; nt < 2; ++nt)
#pragma unroll
        for (int ht = 0; ht < 3; ++ht) D2[nt][ht] = (f32x4){0.f, 0.f, 0.f, 0.f};

#pragma unroll
    for (int ks2 = 0; ks2 < 3; ++ks2) {
        f16x8 B2f[2];
#pragma unroll
        for (int nt = 0; nt < 2; ++nt) {
            U4F bu;
#pragma unroll
            for (int q = 0; q < 4; ++q) {
                // elem pair feats f2 = ks2*32 + lg*8 + 2q, held by lane 16*((lg*2+(q>>1))&3)+l15,
                // reg pk[ks2*2 + (lg>>1)][q&1] of that lane
                int src = ((lg * 2 + (q >> 1)) & 3) * 16 + l15;
                u32 va = (u32)__shfl((int)pk[nt][ks2 * 2][q & 1], src, 64);
                u32 vb = (u32)__shfl((int)pk[nt][ks2 * 2 + 1][q & 1], src, 64);
                bu.u[q] = (lg < 2) ? va : vb;
            }
            B2f[nt] = bu.v;
        }
#pragma unroll
        for (int ht2 = 0; ht2 < 3; ++ht2) {
            int fidx = (ht2 * 3 + ks2) * 64 + l;
            f16x8 wh = *reinterpret_cast<const f16x8*>(&Bp2[fidx * 16]);
            f16x8 wl = *reinterpret_cast<const f16x8*>(&Bp2[fidx * 16 + 8]);
#pragma unroll
            for (int nt = 0; nt < 2; ++nt) {
                D2[nt][ht2] = __builtin_amdgcn_mfma_f32_16x16x32_f16(wh, B2f[nt], D2[nt][ht2], 0, 0, 0);
                D2[nt][ht2] = __builtin_amdgcn_mfma_f32_16x16x32_f16(wl, B2f[nt], D2[nt][ht2], 0, 0, 0);
            }
        }
    }

    // ---- epilogue 2 + layer 3: score(n) = bo + sum_m Wo[m]*prelu(D2[m][n]+b2[m])
    // lane holds m = ht2*16 + lg*4 + jj; reduce over lg groups via shfl_xor 16,32
    float bov = bo[0];
#pragma unroll
    for (int nt = 0; nt < 2; ++nt) {
        float psum = 0.f;
#pragma unroll
        for (int ht2 = 0; ht2 < 3; ++ht2) {
            float4 b4 = *reinterpret_cast<const float4*>(&sb2[ht2 * 16 + lg * 4]);
            float4 a4 = *reinterpret_cast<const float4*>(&sa2[ht2 * 16 + lg * 4]);
            float4 w4 = *reinterpret_cast<const float4*>(&sWo[ht2 * 16 + lg * 4]);
            float v0 = D2[nt][ht2][0] + b4.x;
            float v1 = D2[nt][ht2][1] + b4.y;
            float v2 = D2[nt][ht2][2] + b4.z;
            float v3 = D2[nt][ht2][3] + b4.w;
            v0 = (v0 > 0.f) ? v0 : v0 * a4.x;
            v1 = (v1 > 0.f) ? v1 : v1 * a4.y;
            v2 = (v2 > 0.f) ? v2 : v2 * a4.z;
            v3 = (v3 > 0.f) ? v3 : v3 * a4.w;
            psum += v0 * w4.x + v1 * w4.y + v2 * w4.z + v3 * w4.w;
        }
        psum += __shfl_xor(psum, 16);
        psum += __shfl_xor(psum, 32);
        if (lg == 0) {
            int p = p0 + wv * 32 + nt * 16 + l15;
            float sc = psum + bov;
            scores[p] = (mask[p] == 0) ? NEG_V : sc;
        }
    }
}

// ---------------- softmax over N + weighted value sum
__global__ __launch_bounds__(256) void softmax_out_kernel(
    const float* __restrict__ scores, const float* __restrict__ value,
    float* __restrict__ out) {
    int b = blockIdx.x;
    int tid = threadIdx.x;
    __shared__ float sprob[256];
    __shared__ float sred[8];
    __shared__ float spart[4 * K_SZ];

    float s = (tid < N_SZ) ? scores[b * N_SZ + tid] : -INFINITY;
    float m = s;
#pragma unroll
    for (int off = 32; off >= 1; off >>= 1) m = fmaxf(m, __shfl_xor(m, off));
    if ((tid & 63) == 0) sred[tid >> 6] = m;
    __syncthreads();
    m = fmaxf(fmaxf(sred[0], sred[1]), fmaxf(sred[2], sred[3]));

    float e = (tid < N_SZ) ? expf(s - m) : 0.0f;
    sprob[tid] = e;
    float t = e;
#pragma unroll
    for (int off = 32; off >= 1; off >>= 1) t += __shfl_xor(t, off);
    if ((tid & 63) == 0) sred[4 + (tid >> 6)] = t;
    __syncthreads();
    float inv = 1.0f / (sred[4] + sred[5] + sred[6] + sred[7]);

    int w = tid >> 6;
    int l = tid & 63;
    float acc0 = 0.0f, acc1v = 0.0f;
#pragma unroll 5
    for (int jj = 0; jj < 50; jj += 2) {
        int n = w * 50 + jj;
        acc0  += sprob[n]     * value[((size_t)b * N_SZ + n)     * K_SZ + l];
        acc1v += sprob[n + 1] * value[((size_t)b * N_SZ + n + 1) * K_SZ + l];
    }
    spart[w * K_SZ + l] = acc0 + acc1v;
    __syncthreads();
    if (tid < K_SZ) {
        out[b * K_SZ + tid] =
            (spart[tid] + spart[64 + tid] + spart[128 + tid] + spart[192 + tid]) * inv;
    }
}

extern "C" void kernel_launch(void* const* d_in, const int* in_sizes, int n_in,
                              void* d_out, int out_size, void* d_ws, size_t ws_size,
                              hipStream_t stream) {
    const float* query = (const float*)d_in[0];
    const float* key   = (const float*)d_in[1];
    const float* value = (const float*)d_in[2];
    const int*   mask  = (const int*)d_in[3];
    const float* W1    = (const float*)d_in[4];
    const float* b1    = (const float*)d_in[5];
    const float* a1    = (const float*)d_in[6];
    const float* W2    = (const float*)d_in[7];
    const float* b2    = (const float*)d_in[8];
    const float* a2    = (const float*)d_in[9];
    const float* Wo    = (const float*)d_in[10];
    const float* bo    = (const float*)d_in[11];
    float* out = (float*)d_out;

    float* qW     = (float*)d_ws;                        // B*H1 floats
    float* scores = qW + (size_t)B_SZ * H1;              // B*N floats
    _Float16* Bp1 = (_Float16*)(scores + (size_t)B_SZ * N_SZ);  // 20*64*16 halves
    _Float16* Bp2 = Bp1 + 20 * 64 * 16;                  // 9*64*16 halves

    qw_kernel<<<B_SZ, 128, 0, stream>>>(query, W1, b1, qW);
    prep_bp<<<58, 256, 0, stream>>>(W1, W2, Bp1, Bp2);
    score_mfma<<<(B_SZ * N_SZ) / ROWS, 256, 0, stream>>>(
        query, key, mask, Bp1, Bp2, a1, b2, a2, Wo, bo, qW, scores);
    softmax_out_kernel<<<B_SZ, 256, 0, stream>>>(scores, value, out);
}

// Round 6
// 158.220 us; speedup vs baseline: 1.3156x; 1.0384x over previous
//
#include <hip/hip_runtime.h>
#include <math.h>

#define B_SZ 4096
#define N_SZ 200
#define K_SZ 64
#define H1 80
#define H2 40
#define NEG_V (-4294967295.0f)

typedef _Float16 f16x8 __attribute__((ext_vector_type(8)));
typedef float f32x4 __attribute__((ext_vector_type(4)));
typedef unsigned int u32;

union H2U { _Float16 h[2]; u32 u; };
union U4F { u32 u[4]; f16x8 v; };

// ---------------- qW[b][h] = b1[h] + sum_i q[b][i]*(W1[i][h]+W1[128+i][h])  (exact fp32)
__global__ __launch_bounds__(128) void qw_kernel(const float* __restrict__ query,
                                                 const float* __restrict__ W1,
                                                 const float* __restrict__ b1,
                                                 float* __restrict__ qW) {
    int b = blockIdx.x;
    int tid = threadIdx.x;
    __shared__ float sq[K_SZ];
    if (tid < K_SZ) sq[tid] = query[b * K_SZ + tid];
    __syncthreads();
    if (tid < H1) {
        float acc = b1[tid];
#pragma unroll 8
        for (int i = 0; i < K_SZ; ++i)
            acc += sq[i] * (W1[i * H1 + tid] + W1[(128 + i) * H1 + tid]);
        qW[b * H1 + tid] = acc;
    }
}

// ---------------- pack layer-1/2 weights (A-operand of swapped MFMA), hi|lo interleaved
// frag: lane l, elem j holds W[k = ks*32 + (l>>4)*8 + j][feat = ht*16 + (l&15)]
__global__ __launch_bounds__(256) void prep_bp(const float* __restrict__ W1,
                                               const float* __restrict__ W2,
                                               _Float16* __restrict__ Bp1,
                                               _Float16* __restrict__ Bp2) {
    int idx = blockIdx.x * 256 + threadIdx.x;
    if (idx < 5 * 4 * 64 * 8) {                 // layer1: f = ht*4+ks, 20 frags
        int j = idx & 7, lane = (idx >> 3) & 63, f = idx >> 9;
        int ks = f & 3, ht = f >> 2;
        int k = ks * 32 + (lane >> 4) * 8 + j;  // 0..127: 0-63 k-coef, 64-127 q*k-coef
        int h = ht * 16 + (lane & 15);
        float w = (k < 64) ? (W1[(64 + k) * H1 + h] - W1[(128 + k) * H1 + h])
                           : W1[(192 + (k - 64)) * H1 + h];
        _Float16 hi = (_Float16)w;
        Bp1[(f * 64 + lane) * 16 + j] = hi;
        Bp1[(f * 64 + lane) * 16 + 8 + j] = (_Float16)(w - (float)hi);
    } else {
        int idx2 = idx - 5 * 4 * 64 * 8;
        if (idx2 < 9 * 64 * 8) {                // layer2: f2 = ht2*3+ks2, 9 frags
            int j = idx2 & 7, lane = (idx2 >> 3) & 63, f2 = idx2 >> 9;
            int ks2 = f2 % 3, ht2 = f2 / 3;
            int k2 = ks2 * 32 + (lane >> 4) * 8 + j;
            int m = ht2 * 16 + (lane & 15);
            float w = (k2 < H1 && m < H2) ? W2[k2 * H2 + m] : 0.0f;
            _Float16 hi = (_Float16)w;
            Bp2[(f2 * 64 + lane) * 16 + j] = hi;
            Bp2[(f2 * 64 + lane) * 16 + 8 + j] = (_Float16)(w - (float)hi);
        }
    }
}

// ---------------- fully fused: MLP scores (swapped MFMA) + masked softmax + value sum.
// One b per block: 4 waves; 13 n-tiles of 16 rows (208, rows 200-207 padded) split {4,3,3,3}.
__global__ __launch_bounds__(256, 3) void fused_kernel(
    const float* __restrict__ query, const float* __restrict__ key,
    const float* __restrict__ value, const int* __restrict__ mask,
    const _Float16* __restrict__ Bp1, const _Float16* __restrict__ Bp2,
    const float* __restrict__ a1, const float* __restrict__ b2,
    const float* __restrict__ a2, const float* __restrict__ Wo,
    const float* __restrict__ bo, const float* __restrict__ qW,
    float* __restrict__ out) {
    __shared__ float sq[K_SZ];
    __shared__ float sqW[H1];
    __shared__ float sa1[H1];
    __shared__ float sb2[48], sa2[48], sWo[48];
    __shared__ float sprob[256];       // raw scores, then probabilities
    __shared__ float sred[8];
    __shared__ float spart[4 * K_SZ];

    const int tid = threadIdx.x;
    const int wv = tid >> 6;
    const int l = tid & 63;
    const int l15 = l & 15;
    const int lg = l >> 4;
    const int b = blockIdx.x;
    const int p0 = b * N_SZ;
    const int NT = (wv == 0) ? 4 : 3;               // tiles this wave
    const int tb = (wv == 0) ? 0 : 1 + wv * 3;      // first tile index

    // ---- stage per-b params (tiny)
    if (tid < K_SZ) sq[tid] = query[b * K_SZ + tid];
    if (tid < H1) { sqW[tid] = qW[b * H1 + tid]; sa1[tid] = a1[tid]; }
    if (tid >= 128 && tid < 176) {
        int i = tid - 128;
        sb2[i] = (i < H2) ? b2[i] : 0.0f;
        sa2[i] = (i < H2) ? a2[i] : 0.0f;
        sWo[i] = (i < H2) ? Wo[i] : 0.0f;
    }
    __syncthreads();

    // ---- layer 1: D1[f][n] = sum_k W1c[k][f] * F[k][n]
    f32x4 D1[4][5];
#pragma unroll
    for (int i = 0; i < 4; ++i)
#pragma unroll
        for (int ht = 0; ht < 5; ++ht) D1[i][ht] = (f32x4){0.f, 0.f, 0.f, 0.f};

#pragma unroll
    for (int ksp = 0; ksp < 2; ++ksp) {
        const float* qp = &sq[ksp * 32 + lg * 8];
        float4 q0 = *reinterpret_cast<const float4*>(qp);
        float4 q1 = *reinterpret_cast<const float4*>(qp + 4);
        f16x8 Bk[4], Bqk[4];
#pragma unroll
        for (int i = 0; i < 4; ++i) {
            if (i < NT) {
                int nloc = (tb + i) * 16 + l15;
                int pg = p0 + nloc;
                int pgc = (pg < B_SZ * N_SZ) ? pg : (B_SZ * N_SZ - 1);
                const float* kp = &key[(size_t)pgc * K_SZ + ksp * 32 + lg * 8];
                float4 k0 = *reinterpret_cast<const float4*>(kp);
                float4 k1 = *reinterpret_cast<const float4*>(kp + 4);
                f16x8 bk, bq;
                bk[0] = (_Float16)k0.x; bk[1] = (_Float16)k0.y; bk[2] = (_Float16)k0.z; bk[3] = (_Float16)k0.w;
                bk[4] = (_Float16)k1.x; bk[5] = (_Float16)k1.y; bk[6] = (_Float16)k1.z; bk[7] = (_Float16)k1.w;
                bq[0] = (_Float16)(q0.x * k0.x); bq[1] = (_Float16)(q0.y * k0.y);
                bq[2] = (_Float16)(q0.z * k0.z); bq[3] = (_Float16)(q0.w * k0.w);
                bq[4] = (_Float16)(q1.x * k1.x); bq[5] = (_Float16)(q1.y * k1.y);
                bq[6] = (_Float16)(q1.z * k1.z); bq[7] = (_Float16)(q1.w * k1.w);
                Bk[i] = bk; Bqk[i] = bq;
            }
        }
#pragma unroll
        for (int ht = 0; ht < 5; ++ht) {
#pragma unroll
            for (int s = 0; s < 2; ++s) {
                int kk = ksp + s * 2;            // weight k-tile index
                int fidx = (ht * 4 + kk) * 64 + l;
                f16x8 wh = *reinterpret_cast<const f16x8*>(&Bp1[fidx * 16]);
                f16x8 wl = *reinterpret_cast<const f16x8*>(&Bp1[fidx * 16 + 8]);
#pragma unroll
                for (int i = 0; i < 4; ++i) {
                    if (i < NT) {
                        f16x8 bb = (s == 0) ? Bk[i] : Bqk[i];
                        D1[i][ht] = __builtin_amdgcn_mfma_f32_16x16x32_f16(wh, bb, D1[i][ht], 0, 0, 0);
                        D1[i][ht] = __builtin_amdgcn_mfma_f32_16x16x32_f16(wl, bb, D1[i][ht], 0, 0, 0);
                    }
                }
            }
        }
    }

    // ---- epilogue 1 (in-register): h1 = prelu(D1 + qW), pack to fp16 pairs
    u32 pk[4][6][2];
#pragma unroll
    for (int i = 0; i < 4; ++i) {
        if (i < NT) {
#pragma unroll
            for (int ht = 0; ht < 5; ++ht) {
                float4 qw4 = *reinterpret_cast<const float4*>(&sqW[ht * 16 + lg * 4]);
                float4 aa4 = *reinterpret_cast<const float4*>(&sa1[ht * 16 + lg * 4]);
                float h0 = D1[i][ht][0] + qw4.x;
                float h1v = D1[i][ht][1] + qw4.y;
                float h2 = D1[i][ht][2] + qw4.z;
                float h3 = D1[i][ht][3] + qw4.w;
                h0 = (h0 > 0.f) ? h0 : h0 * aa4.x;
                h1v = (h1v > 0.f) ? h1v : h1v * aa4.y;
                h2 = (h2 > 0.f) ? h2 : h2 * aa4.z;
                h3 = (h3 > 0.f) ? h3 : h3 * aa4.w;
                H2U u0, u1;
                u0.h[0] = (_Float16)h0; u0.h[1] = (_Float16)h1v;
                u1.h[0] = (_Float16)h2; u1.h[1] = (_Float16)h3;
                pk[i][ht][0] = u0.u;
                pk[i][ht][1] = u1.u;
            }
            pk[i][5][0] = 0u; pk[i][5][1] = 0u;   // zero-pad feats 80..95
        }
    }

    // ---- layer 2: D2[m][n] = sum_k2 W2[k2][m] * h1[k2][n]
    f32x4 D2[4][3];
#pragma unroll
    for (int i = 0; i < 4; ++i)
#pragma unroll
        for (int ht = 0; ht < 3; ++ht) D2[i][ht] = (f32x4){0.f, 0.f, 0.f, 0.f};

#pragma unroll
    for (int ks2 = 0; ks2 < 3; ++ks2) {
        f16x8 B2f[4];
#pragma unroll
        for (int i = 0; i < 4; ++i) {
            if (i < NT) {
                U4F bu;
#pragma unroll
                for (int q = 0; q < 4; ++q) {
                    int src = ((lg * 2 + (q >> 1)) & 3) * 16 + l15;
                    u32 va = (u32)__shfl((int)pk[i][ks2 * 2][q & 1], src, 64);
                    u32 vb = (u32)__shfl((int)pk[i][ks2 * 2 + 1][q & 1], src, 64);
                    bu.u[q] = (lg < 2) ? va : vb;
                }
                B2f[i] = bu.v;
            }
        }
#pragma unroll
        for (int ht2 = 0; ht2 < 3; ++ht2) {
            int fidx = (ht2 * 3 + ks2) * 64 + l;
            f16x8 wh = *reinterpret_cast<const f16x8*>(&Bp2[fidx * 16]);
            f16x8 wl = *reinterpret_cast<const f16x8*>(&Bp2[fidx * 16 + 8]);
#pragma unroll
            for (int i = 0; i < 4; ++i) {
                if (i < NT) {
                    D2[i][ht2] = __builtin_amdgcn_mfma_f32_16x16x32_f16(wh, B2f[i], D2[i][ht2], 0, 0, 0);
                    D2[i][ht2] = __builtin_amdgcn_mfma_f32_16x16x32_f16(wl, B2f[i], D2[i][ht2], 0, 0, 0);
                }
            }
        }
    }

    // ---- epilogue 2 + layer 3: score(n) = bo + sum_m Wo[m]*prelu(D2[m][n]+b2[m])
    float bov = bo[0];
#pragma unroll
    for (int i = 0; i < 4; ++i) {
        if (i < NT) {
            float psum = 0.f;
#pragma unroll
            for (int ht2 = 0; ht2 < 3; ++ht2) {
                float4 b4 = *reinterpret_cast<const float4*>(&sb2[ht2 * 16 + lg * 4]);
                float4 a4 = *reinterpret_cast<const float4*>(&sa2[ht2 * 16 + lg * 4]);
                float4 w4 = *reinterpret_cast<const float4*>(&sWo[ht2 * 16 + lg * 4]);
                float v0 = D2[i][ht2][0] + b4.x;
                float v1 = D2[i][ht2][1] + b4.y;
                float v2 = D2[i][ht2][2] + b4.z;
                float v3 = D2[i][ht2][3] + b4.w;
                v0 = (v0 > 0.f) ? v0 : v0 * a4.x;
                v1 = (v1 > 0.f) ? v1 : v1 * a4.y;
                v2 = (v2 > 0.f) ? v2 : v2 * a4.z;
                v3 = (v3 > 0.f) ? v3 : v3 * a4.w;
                psum += v0 * w4.x + v1 * w4.y + v2 * w4.z + v3 * w4.w;
            }
            psum += __shfl_xor(psum, 16);
            psum += __shfl_xor(psum, 32);
            if (lg == 0) {
                int nloc = (tb + i) * 16 + l15;
                float sv;
                if (nloc < N_SZ) sv = (mask[p0 + nloc] == 0) ? NEG_V : (psum + bov);
                else sv = -INFINITY;
                sprob[nloc] = sv;
            }
        }
    }
    __syncthreads();

    // ---- softmax over the 208 staged scores (pads are -inf)
    float s = (tid < 208) ? sprob[tid] : -INFINITY;
    float m = s;
#pragma unroll
    for (int off = 32; off >= 1; off >>= 1) m = fmaxf(m, __shfl_xor(m, off));
    if ((tid & 63) == 0) sred[tid >> 6] = m;
    __syncthreads();
    m = fmaxf(fmaxf(sred[0], sred[1]), fmaxf(sred[2], sred[3]));

    float e = (tid < 208) ? expf(s - m) : 0.0f;
    sprob[tid] = e;
    float t = e;
#pragma unroll
    for (int off = 32; off >= 1; off >>= 1) t += __shfl_xor(t, off);
    if ((tid & 63) == 0) sred[4 + (tid >> 6)] = t;
    __syncthreads();
    float inv = 1.0f / (sred[4] + sred[5] + sred[6] + sred[7]);

    // ---- weighted value sum: wave w covers n = [50w, 50w+50), lane = k index
    float acc0 = 0.0f, acc1v = 0.0f;
#pragma unroll 5
    for (int jj = 0; jj < 50; jj += 2) {
        int n = wv * 50 + jj;
        acc0  += sprob[n]     * value[((size_t)p0 + n)     * K_SZ + l];
        acc1v += sprob[n + 1] * value[((size_t)p0 + n + 1) * K_SZ + l];
    }
    spart[wv * K_SZ + l] = acc0 + acc1v;
    __syncthreads();
    if (tid < K_SZ) {
        out[b * K_SZ + tid] =
            (spart[tid] + spart[64 + tid] + spart[128 + tid] + spart[192 + tid]) * inv;
    }
}

extern "C" void kernel_launch(void* const* d_in, const int* in_sizes, int n_in,
                              void* d_out, int out_size, void* d_ws, size_t ws_size,
                              hipStream_t stream) {
    const float* query = (const float*)d_in[0];
    const float* key   = (const float*)d_in[1];
    const float* value = (const float*)d_in[2];
    const int*   mask  = (const int*)d_in[3];
    const float* W1    = (const float*)d_in[4];
    const float* b1    = (const float*)d_in[5];
    const float* a1    = (const float*)d_in[6];
    const float* W2    = (const float*)d_in[7];
    const float* b2    = (const float*)d_in[8];
    const float* a2    = (const float*)d_in[9];
    const float* Wo    = (const float*)d_in[10];
    const float* bo    = (const float*)d_in[11];
    float* out = (float*)d_out;

    float* qW     = (float*)d_ws;                        // B*H1 floats
    _Float16* Bp1 = (_Float16*)(qW + (size_t)B_SZ * H1); // 20*64*16 halves
    _Float16* Bp2 = Bp1 + 20 * 64 * 16;                  // 9*64*16 halves

    qw_kernel<<<B_SZ, 128, 0, stream>>>(query, W1, b1, qW);
    prep_bp<<<58, 256, 0, stream>>>(W1, W2, Bp1, Bp2);
    fused_kernel<<<B_SZ, 256, 0, stream>>>(
        query, key, value, mask, Bp1, Bp2, a1, b2, a2, Wo, bo, qW, out);
}